// Round 6
// baseline (378.366 us; speedup 1.0000x reference)
//
#include <hip/hip_runtime.h>
#include <hip/hip_bf16.h>

// Fused Linear([16,8192,256] x [256,256]^T) + per-batch BatchNorm over N=8192.
// bf16x3 split-GEMM (hi*hi + hi*lo + lo*hi) => fp32-class accuracy on MFMA.
// Bias b dropped: BN mean-subtraction cancels any per-feature constant.
//
// R3: root cause of R0-R2 slowness = in-GEMM fp32->bf16 split VALU (staging
// VALU > MFMA work) + redundant X staging + global B loads in inner loop.
// Fix: pre-split X and W ONCE into bf16 hi/lo stored in PRE-SWIZZLED tile
// images; GEMM stages all four tiles via global_load_lds (width 16, zero
// VALU), reads fragments with matching XOR swizzle (2-way conflicts only).
// R4/R5: identical resubmits (GPU acquisition timeouts - never ran).

typedef __attribute__((ext_vector_type(8))) __bf16 bf16x8;
typedef __attribute__((ext_vector_type(4))) float f32x4;
typedef __attribute__((ext_vector_type(8))) unsigned short us8;

#define BDIM   16
#define NDIM   8192
#define FIN    256
#define FOUT   256
#define BM     128
#define BN     128
#define BK     64
#define NTH    256
#define NRBLK  1024               // (BDIM*NDIM)/BM
#define NCBLK  2                  // FOUT/BN
#define NKS    4                  // FIN/BK
#define TILEB  16384              // 128 rows x 64 k x 2B (one hi or lo tile)

// Swizzled byte offset inside a 128x64-bf16 tile: row r (0..127), 16B chunk c (0..7).
__device__ __forceinline__ int swz(int r, int c) {
  return r * 128 + ((c * 16) ^ ((r & 7) << 4));
}

__device__ __forceinline__ void split8(const float4 v0, const float4 v1,
                                       us8& h, us8& l) {
  float f[8] = {v0.x, v0.y, v0.z, v0.w, v1.x, v1.y, v1.z, v1.w};
#pragma unroll
  for (int i = 0; i < 8; ++i) {
    unsigned int u = __float_as_uint(f[i]);
    h[i] = (unsigned short)(u >> 16);
    float rem = f[i] - __uint_as_float(u & 0xFFFF0000u);
    l[i] = (unsigned short)(__float_as_uint(rem) >> 16);
  }
}

__device__ __forceinline__ void gload_lds16(const void* g, void* l) {
  __builtin_amdgcn_global_load_lds(
      (const __attribute__((address_space(1))) unsigned int*)g,
      (__attribute__((address_space(3))) unsigned int*)l, 16, 0, 0);
}

// X [131072][256] fp32 -> Xh/Xl bf16 tile images [rblk][ks][swizzled 128x64].
__global__ void split_x(const float* __restrict__ X,
                        unsigned short* __restrict__ Xh,
                        unsigned short* __restrict__ Xl) {
  const int total = (BDIM * NDIM) * (FIN / 8);  // 4,194,304 16B-chunks
  for (int i = blockIdx.x * blockDim.x + threadIdx.x; i < total;
       i += gridDim.x * blockDim.x) {
    int row = i >> 5;
    int rem = i & 31;
    int ks = rem >> 3, c = rem & 7;
    const float4* g = (const float4*)(X + (size_t)row * FIN + ks * BK + c * 8);
    float4 v0 = g[0], v1 = g[1];
    us8 h, l;
    split8(v0, v1, h, l);
    size_t tb = ((size_t)(row >> 7) * NKS + ks) * TILEB;
    int boff = swz(row & 127, c);
    *(us8*)((char*)Xh + tb + boff) = h;
    *(us8*)((char*)Xl + tb + boff) = l;
  }
}

// W [256][256] fp32 (row = out col) -> Wh/Wl tile images [cblk][ks][...].
__global__ void split_w(const float* __restrict__ W,
                        unsigned short* __restrict__ Wh,
                        unsigned short* __restrict__ Wl) {
  int i = blockIdx.x * blockDim.x + threadIdx.x;  // 0..8191
  int row = i >> 5;
  int rem = i & 31;
  int ks = rem >> 3, c = rem & 7;
  const float4* g = (const float4*)(W + (size_t)row * FIN + ks * BK + c * 8);
  float4 v0 = g[0], v1 = g[1];
  us8 h, l;
  split8(v0, v1, h, l);
  size_t tb = ((size_t)(row >> 7) * NKS + ks) * TILEB;
  int boff = swz(row & 127, c);
  *(us8*)((char*)Wh + tb + boff) = h;
  *(us8*)((char*)Wl + tb + boff) = l;
}

// MODE 0: write y + transposed partial stats. MODE 1: stats only.
// MODE 2: apply per-(b,o) scale/shift, write normalized out.
template <int MODE>
__global__ __launch_bounds__(NTH, 2)
void fused_gemm(const unsigned short* __restrict__ Xh,
                const unsigned short* __restrict__ Xl,
                const unsigned short* __restrict__ Wh,
                const unsigned short* __restrict__ Wl,
                float* __restrict__ Y,
                float* __restrict__ P1, float* __restrict__ P2,
                const float* __restrict__ Sc, const float* __restrict__ Tc) {
  __shared__ __align__(16) char lds[65536];
  char* Abh = lds;
  char* Abl = lds + 16384;
  char* Bbh = lds + 32768;
  char* Bbl = lds + 49152;

  const int tid  = threadIdx.x;
  const int rblk = blockIdx.x;   // 0..1023
  const int cblk = blockIdx.y;   // 0..1
  const int wid = tid >> 6, lane = tid & 63;
  const int wr = wid >> 1, wc = wid & 1;   // 2x2 waves, wave tile 64x64
  const int lg = lane >> 4, lr = lane & 15;

  f32x4 acc[4][4];
#pragma unroll
  for (int m = 0; m < 4; ++m)
#pragma unroll
    for (int n = 0; n < 4; ++n) acc[m][n] = f32x4{0.f, 0.f, 0.f, 0.f};

  const char* gAh = (const char*)Xh + (size_t)rblk * NKS * TILEB;
  const char* gAl = (const char*)Xl + (size_t)rblk * NKS * TILEB;
  const char* gBh = (const char*)Wh + (size_t)cblk * NKS * TILEB;
  const char* gBl = (const char*)Wl + (size_t)cblk * NKS * TILEB;

  for (int ks = 0; ks < NKS; ++ks) {
    const size_t kb = (size_t)ks * TILEB;
    // ---- stage 4 x 16KB tiles, pure DMA (no VALU) ----
#pragma unroll
    for (int j = 0; j < 4; ++j) {
      int so = (wid * 4 + j) * 1024;     // 1KB segment per wave-instr
      int go = so + lane * 16;
      gload_lds16(gAh + kb + go, Abh + so);
      gload_lds16(gAl + kb + go, Abl + so);
      gload_lds16(gBh + kb + go, Bbh + so);
      gload_lds16(gBl + kb + go, Bbl + so);
    }
    __syncthreads();
    // ---- compute ----
#pragma unroll
    for (int kk = 0; kk < 2; ++kk) {
      bf16x8 ah[4], al[4], bh[4], bl[4];
#pragma unroll
      for (int m = 0; m < 4; ++m) {
        int boff = swz(wr * 64 + m * 16 + lr, kk * 4 + lg);
        ah[m] = *(const bf16x8*)(Abh + boff);
        al[m] = *(const bf16x8*)(Abl + boff);
      }
#pragma unroll
      for (int n = 0; n < 4; ++n) {
        int boff = swz(wc * 64 + n * 16 + lr, kk * 4 + lg);
        bh[n] = *(const bf16x8*)(Bbh + boff);
        bl[n] = *(const bf16x8*)(Bbl + boff);
      }
#pragma unroll
      for (int m = 0; m < 4; ++m)
#pragma unroll
        for (int n = 0; n < 4; ++n) {
          acc[m][n] = __builtin_amdgcn_mfma_f32_16x16x32_bf16(ah[m], bh[n], acc[m][n], 0, 0, 0);
          acc[m][n] = __builtin_amdgcn_mfma_f32_16x16x32_bf16(ah[m], bl[n], acc[m][n], 0, 0, 0);
          acc[m][n] = __builtin_amdgcn_mfma_f32_16x16x32_bf16(al[m], bh[n], acc[m][n], 0, 0, 0);
        }
    }
    __syncthreads();
  }

  const size_t rowBase = (size_t)rblk * BM;
  const int colBase = cblk * BN;

  if (MODE == 0) {
#pragma unroll
    for (int m = 0; m < 4; ++m) {
      size_t row = rowBase + wr * 64 + m * 16 + lg * 4;
#pragma unroll
      for (int n = 0; n < 4; ++n) {
        int col = colBase + wc * 64 + n * 16 + lr;
#pragma unroll
        for (int r = 0; r < 4; ++r)
          Y[(row + r) * (size_t)FOUT + col] = acc[m][n][r];
      }
    }
  }

  if (MODE <= 1) {
    // per-column partials over this block's 128 rows -> P[o][rblk]
    float ps1[4], ps2[4];
#pragma unroll
    for (int n = 0; n < 4; ++n) {
      ps1[n] = 0.f; ps2[n] = 0.f;
#pragma unroll
      for (int m = 0; m < 4; ++m)
#pragma unroll
        for (int r = 0; r < 4; ++r) {
          float v = acc[m][n][r];
          ps1[n] += v; ps2[n] += v * v;
        }
      ps1[n] += __shfl_xor(ps1[n], 16);
      ps1[n] += __shfl_xor(ps1[n], 32);
      ps2[n] += __shfl_xor(ps2[n], 16);
      ps2[n] += __shfl_xor(ps2[n], 32);
    }
    __syncthreads();
    float* red = (float*)lds;   // [2][4 waves][64 cols]
    if (lane < 16) {
#pragma unroll
      for (int n = 0; n < 4; ++n) {
        red[wid * 64 + n * 16 + lr]       = ps1[n];
        red[256 + wid * 64 + n * 16 + lr] = ps2[n];
      }
    }
    __syncthreads();
    if (tid < BN) {
      int wcs = tid >> 6, j = tid & 63;  // waves wcs and 2+wcs share col tid
      float s1 = red[wcs * 64 + j] + red[(2 + wcs) * 64 + j];
      float s2 = red[256 + wcs * 64 + j] + red[256 + (2 + wcs) * 64 + j];
      P1[(size_t)(colBase + tid) * NRBLK + rblk] = s1;
      P2[(size_t)(colBase + tid) * NRBLK + rblk] = s2;
    }
  }

  if (MODE == 2) {
    const int b = rblk >> 6;   // 64 row-blocks per batch
#pragma unroll
    for (int n = 0; n < 4; ++n) {
      int col  = colBase + wc * 64 + n * 16 + lr;
      float sc = Sc[b * FOUT + col];
      float tc = Tc[b * FOUT + col];
#pragma unroll
      for (int m = 0; m < 4; ++m) {
        size_t row = rowBase + wr * 64 + m * 16 + lg * 4;
#pragma unroll
        for (int r = 0; r < 4; ++r)
          Y[(row + r) * (size_t)FOUT + col] = fmaf(acc[m][n][r], sc, tc);
      }
    }
  }
}

// One wave per (b,o); coalesced 64-lane read over rblk, shuffle reduce.
__global__ void reduce_stats(const float* __restrict__ P1, const float* __restrict__ P2,
                             const float* __restrict__ gamma, const float* __restrict__ beta,
                             float* __restrict__ Sc, float* __restrict__ Tc) {
  int p = blockIdx.x * 4 + (threadIdx.x >> 6);   // 0..4095 = (b,o)
  int lane = threadIdx.x & 63;
  int b = p >> 8, o = p & 255;
  size_t base = (size_t)o * NRBLK + b * 64;
  float s1 = P1[base + lane];
  float s2 = P2[base + lane];
#pragma unroll
  for (int off = 32; off; off >>= 1) {
    s1 += __shfl_xor(s1, off);
    s2 += __shfl_xor(s2, off);
  }
  if (lane == 0) {
    float mean = s1 * (1.f / (float)NDIM);
    float var  = s2 * (1.f / (float)NDIM) - mean * mean;
    float g    = gamma[o] * rsqrtf(var + 1e-5f);
    Sc[p] = g;
    Tc[p] = beta[o] - mean * g;
  }
}

// Elementwise normalize of materialized y (Plan A).
__global__ void normalize_y(const float4* __restrict__ Yv,
                            const float* __restrict__ Sc, const float* __restrict__ Tc,
                            float4* __restrict__ Ov) {
  const int total = (BDIM * NDIM * FOUT) / 4;  // 8,388,608
  for (int i = blockIdx.x * blockDim.x + threadIdx.x; i < total;
       i += gridDim.x * blockDim.x) {
    float4 y = Yv[i];
    size_t e = (size_t)i * 4;
    int o = (int)(e & 255);
    int b = (int)(e >> 21);
    const float4 s = *(const float4*)(Sc + b * 256 + o);
    const float4 t = *(const float4*)(Tc + b * 256 + o);
    float4 r;
    r.x = fmaf(y.x, s.x, t.x);
    r.y = fmaf(y.y, s.y, t.y);
    r.z = fmaf(y.z, s.z, t.z);
    r.w = fmaf(y.w, s.w, t.w);
    Ov[i] = r;
  }
}

extern "C" void kernel_launch(void* const* d_in, const int* in_sizes, int n_in,
                              void* d_out, int out_size, void* d_ws, size_t ws_size,
                              hipStream_t stream) {
  const float* X     = (const float*)d_in[0];
  const float* W     = (const float*)d_in[1];
  // d_in[2] = bias: cancelled exactly by BN mean subtraction.
  const float* gamma = (const float*)d_in[3];
  const float* beta  = (const float*)d_in[4];
  float* out = (float*)d_out;
  char* ws = (char*)d_ws;

  const size_t yB  = (size_t)BDIM * NDIM * FOUT * 4;   // 134,217,728
  const size_t pB  = (size_t)FOUT * NRBLK * 4;         // 1,048,576
  const size_t scB = 4096 * 4;                         // 16,384
  const size_t wB  = (size_t)FOUT * FIN * 2;           // 131,072
  const size_t xB  = (size_t)BDIM * NDIM * FIN * 2;    // 67,108,864

  const size_t needAp = 2 * pB + 2 * scB + 2 * wB + 2 * xB;  // ~136.6 MB
  const size_t needA  = needAp + yB;                         // ~270.8 MB

  dim3 grid(NRBLK, NCBLK), blk(NTH);
  if (ws_size >= needA) {
    // Plan A: materialize y in ws, one GEMM pass + streaming normalize.
    float* Y  = (float*)ws;
    float* P1 = (float*)(ws + yB);
    float* P2 = (float*)(ws + yB + pB);
    float* Sc = (float*)(ws + yB + 2 * pB);
    float* Tc = (float*)(ws + yB + 2 * pB + scB);
    unsigned short* Wh = (unsigned short*)(ws + yB + 2 * pB + 2 * scB);
    unsigned short* Wl = (unsigned short*)(ws + yB + 2 * pB + 2 * scB + wB);
    unsigned short* Xh = (unsigned short*)(ws + yB + 2 * pB + 2 * scB + 2 * wB);
    unsigned short* Xl = (unsigned short*)(ws + yB + 2 * pB + 2 * scB + 2 * wB + xB);
    split_w<<<32, 256, 0, stream>>>(W, Wh, Wl);
    split_x<<<2048, 256, 0, stream>>>(X, Xh, Xl);
    fused_gemm<0><<<grid, blk, 0, stream>>>(Xh, Xl, Wh, Wl, Y, P1, P2, nullptr, nullptr);
    reduce_stats<<<1024, 256, 0, stream>>>(P1, P2, gamma, beta, Sc, Tc);
    normalize_y<<<4096, 256, 0, stream>>>((const float4*)Y, Sc, Tc, (float4*)out);
  } else {
    // Plan A': stats pass + recompute pass (needs ~136.6 MB ws).
    float* P1 = (float*)ws;
    float* P2 = (float*)(ws + pB);
    float* Sc = (float*)(ws + 2 * pB);
    float* Tc = (float*)(ws + 2 * pB + scB);
    unsigned short* Wh = (unsigned short*)(ws + 2 * pB + 2 * scB);
    unsigned short* Wl = (unsigned short*)(ws + 2 * pB + 2 * scB + wB);
    unsigned short* Xh = (unsigned short*)(ws + 2 * pB + 2 * scB + 2 * wB);
    unsigned short* Xl = (unsigned short*)(ws + 2 * pB + 2 * scB + 2 * wB + xB);
    split_w<<<32, 256, 0, stream>>>(W, Wh, Wl);
    split_x<<<2048, 256, 0, stream>>>(X, Xh, Xl);
    fused_gemm<1><<<grid, blk, 0, stream>>>(Xh, Xl, Wh, Wl, nullptr, P1, P2, nullptr, nullptr);
    reduce_stats<<<1024, 256, 0, stream>>>(P1, P2, gamma, beta, Sc, Tc);
    fused_gemm<2><<<grid, blk, 0, stream>>>(Xh, Xl, Wh, Wl, out, P1, P2, Sc, Tc);
  }
}

// Round 7
// 370.766 us; speedup vs baseline: 1.0205x; 1.0205x over previous
//
#include <hip/hip_runtime.h>
#include <hip/hip_bf16.h>

// Fused Linear([16,8192,256] x [256,256]^T) + per-batch BatchNorm over N=8192.
// bf16x3 split-GEMM (hi*hi + hi*lo + lo*hi) => fp32-class accuracy on MFMA.
// Bias b dropped: BN mean-subtraction cancels any per-feature constant.
//
// R6 measured: gemm 87us, MfmaUtil 23%, Occupancy 18% (LDS 64KB -> 2 blk/CU).
// R7: BK 64->32 => LDS 32KB => 5 blocks/CU (20 waves, 62%) at VGPR~88.
// Swizzle re-derived for 64B row stride: c' = c ^ (r&3) (16B chunks) =>
// wave ds_read_b128 covers a 16-row 1KB span exactly once (conflict-free).

typedef __attribute__((ext_vector_type(8))) __bf16 bf16x8;
typedef __attribute__((ext_vector_type(4))) float f32x4;
typedef __attribute__((ext_vector_type(8))) unsigned short us8;

#define BDIM   16
#define NDIM   8192
#define FIN    256
#define FOUT   256
#define BM     128
#define BN     128
#define BK     32
#define NTH    256
#define NRBLK  1024               // (BDIM*NDIM)/BM
#define NCBLK  2                  // FOUT/BN
#define NKS    8                  // FIN/BK
#define TILEB  8192               // 128 rows x 32 k x 2B (one hi or lo tile)

// Swizzled byte offset inside a 128x32-bf16 tile: row r (0..127), 16B chunk c (0..3).
__device__ __forceinline__ int swz(int r, int c) {
  return r * 64 + ((c ^ (r & 3)) << 4);
}

__device__ __forceinline__ void split8(const float4 v0, const float4 v1,
                                       us8& h, us8& l) {
  float f[8] = {v0.x, v0.y, v0.z, v0.w, v1.x, v1.y, v1.z, v1.w};
#pragma unroll
  for (int i = 0; i < 8; ++i) {
    unsigned int u = __float_as_uint(f[i]);
    h[i] = (unsigned short)(u >> 16);
    float rem = f[i] - __uint_as_float(u & 0xFFFF0000u);
    l[i] = (unsigned short)(__float_as_uint(rem) >> 16);
  }
}

__device__ __forceinline__ void gload_lds16(const void* g, void* l) {
  __builtin_amdgcn_global_load_lds(
      (const __attribute__((address_space(1))) unsigned int*)g,
      (__attribute__((address_space(3))) unsigned int*)l, 16, 0, 0);
}

// X [131072][256] fp32 -> Xh/Xl bf16 tile images [rblk][ks][swizzled 128x32].
__global__ void split_x(const float* __restrict__ X,
                        unsigned short* __restrict__ Xh,
                        unsigned short* __restrict__ Xl) {
  const int total = (BDIM * NDIM) * (FIN / 8);  // 4,194,304 16B-chunks
  for (int i = blockIdx.x * blockDim.x + threadIdx.x; i < total;
       i += gridDim.x * blockDim.x) {
    int row = i >> 5;
    int cg  = i & 31;                 // global 16B chunk 0..31
    int ks = cg >> 2, c = cg & 3;
    const float4* g = (const float4*)(X + (size_t)row * FIN + ks * BK + c * 8);
    float4 v0 = g[0], v1 = g[1];
    us8 h, l;
    split8(v0, v1, h, l);
    size_t tb = ((size_t)(row >> 7) * NKS + ks) * TILEB;
    int boff = swz(row & 127, c);
    *(us8*)((char*)Xh + tb + boff) = h;
    *(us8*)((char*)Xl + tb + boff) = l;
  }
}

// W [256][256] fp32 (row = out col) -> Wh/Wl tile images [cblk][ks][...].
__global__ void split_w(const float* __restrict__ W,
                        unsigned short* __restrict__ Wh,
                        unsigned short* __restrict__ Wl) {
  int i = blockIdx.x * blockDim.x + threadIdx.x;  // 0..8191
  int row = i >> 5;
  int cg  = i & 31;
  int ks = cg >> 2, c = cg & 3;
  const float4* g = (const float4*)(W + (size_t)row * FIN + ks * BK + c * 8);
  float4 v0 = g[0], v1 = g[1];
  us8 h, l;
  split8(v0, v1, h, l);
  size_t tb = ((size_t)(row >> 7) * NKS + ks) * TILEB;
  int boff = swz(row & 127, c);
  *(us8*)((char*)Wh + tb + boff) = h;
  *(us8*)((char*)Wl + tb + boff) = l;
}

// MODE 0: write y + transposed partial stats. MODE 1: stats only.
// MODE 2: apply per-(b,o) scale/shift, write normalized out.
template <int MODE>
__global__ __launch_bounds__(NTH, 4)
void fused_gemm(const unsigned short* __restrict__ Xh,
                const unsigned short* __restrict__ Xl,
                const unsigned short* __restrict__ Wh,
                const unsigned short* __restrict__ Wl,
                float* __restrict__ Y,
                float* __restrict__ P1, float* __restrict__ P2,
                const float* __restrict__ Sc, const float* __restrict__ Tc) {
  __shared__ __align__(16) char lds[4 * TILEB];  // 32 KB
  char* Abh = lds;
  char* Abl = lds + TILEB;
  char* Bbh = lds + 2 * TILEB;
  char* Bbl = lds + 3 * TILEB;

  const int tid  = threadIdx.x;
  const int rblk = blockIdx.x;   // 0..1023
  const int cblk = blockIdx.y;   // 0..1
  const int wid = tid >> 6, lane = tid & 63;
  const int wr = wid >> 1, wc = wid & 1;   // 2x2 waves, wave tile 64x64
  const int lg = lane >> 4, lr = lane & 15;

  f32x4 acc[4][4];
#pragma unroll
  for (int m = 0; m < 4; ++m)
#pragma unroll
    for (int n = 0; n < 4; ++n) acc[m][n] = f32x4{0.f, 0.f, 0.f, 0.f};

  const char* gAh = (const char*)Xh + (size_t)rblk * NKS * TILEB;
  const char* gAl = (const char*)Xl + (size_t)rblk * NKS * TILEB;
  const char* gBh = (const char*)Wh + (size_t)cblk * NKS * TILEB;
  const char* gBl = (const char*)Wl + (size_t)cblk * NKS * TILEB;

  for (int ks = 0; ks < NKS; ++ks) {
    const size_t kb = (size_t)ks * TILEB;
    // ---- stage 4 x 8KB tiles, pure DMA (no VALU) ----
#pragma unroll
    for (int j = 0; j < 2; ++j) {
      int so = (wid * 2 + j) * 1024;     // 1KB segment per wave-instr
      int go = so + lane * 16;
      gload_lds16(gAh + kb + go, Abh + so);
      gload_lds16(gAl + kb + go, Abl + so);
      gload_lds16(gBh + kb + go, Bbh + so);
      gload_lds16(gBl + kb + go, Bbl + so);
    }
    __syncthreads();
    // ---- compute: one K=32 slab, 4x4 fragments, 3 products ----
    bf16x8 ah[4], al[4], bh[4], bl[4];
#pragma unroll
    for (int m = 0; m < 4; ++m) {
      int boff = swz(wr * 64 + m * 16 + lr, lg);
      ah[m] = *(const bf16x8*)(Abh + boff);
      al[m] = *(const bf16x8*)(Abl + boff);
    }
#pragma unroll
    for (int n = 0; n < 4; ++n) {
      int boff = swz(wc * 64 + n * 16 + lr, lg);
      bh[n] = *(const bf16x8*)(Bbh + boff);
      bl[n] = *(const bf16x8*)(Bbl + boff);
    }
#pragma unroll
    for (int m = 0; m < 4; ++m)
#pragma unroll
      for (int n = 0; n < 4; ++n) {
        acc[m][n] = __builtin_amdgcn_mfma_f32_16x16x32_bf16(ah[m], bh[n], acc[m][n], 0, 0, 0);
        acc[m][n] = __builtin_amdgcn_mfma_f32_16x16x32_bf16(ah[m], bl[n], acc[m][n], 0, 0, 0);
        acc[m][n] = __builtin_amdgcn_mfma_f32_16x16x32_bf16(al[m], bh[n], acc[m][n], 0, 0, 0);
      }
    __syncthreads();
  }

  const size_t rowBase = (size_t)rblk * BM;
  const int colBase = cblk * BN;

  if (MODE == 0) {
#pragma unroll
    for (int m = 0; m < 4; ++m) {
      size_t row = rowBase + wr * 64 + m * 16 + lg * 4;
#pragma unroll
      for (int n = 0; n < 4; ++n) {
        int col = colBase + wc * 64 + n * 16 + lr;
#pragma unroll
        for (int r = 0; r < 4; ++r)
          Y[(row + r) * (size_t)FOUT + col] = acc[m][n][r];
      }
    }
  }

  if (MODE <= 1) {
    // per-column partials over this block's 128 rows -> P[o][rblk]
    float ps1[4], ps2[4];
#pragma unroll
    for (int n = 0; n < 4; ++n) {
      ps1[n] = 0.f; ps2[n] = 0.f;
#pragma unroll
      for (int m = 0; m < 4; ++m)
#pragma unroll
        for (int r = 0; r < 4; ++r) {
          float v = acc[m][n][r];
          ps1[n] += v; ps2[n] += v * v;
        }
      ps1[n] += __shfl_xor(ps1[n], 16);
      ps1[n] += __shfl_xor(ps1[n], 32);
      ps2[n] += __shfl_xor(ps2[n], 16);
      ps2[n] += __shfl_xor(ps2[n], 32);
    }
    __syncthreads();
    float* red = (float*)lds;   // [2][4 waves][64 cols]
    if (lane < 16) {
#pragma unroll
      for (int n = 0; n < 4; ++n) {
        red[wid * 64 + n * 16 + lr]       = ps1[n];
        red[256 + wid * 64 + n * 16 + lr] = ps2[n];
      }
    }
    __syncthreads();
    if (tid < BN) {
      int wcs = tid >> 6, j = tid & 63;  // waves wcs and 2+wcs share col tid
      float s1 = red[wcs * 64 + j] + red[(2 + wcs) * 64 + j];
      float s2 = red[256 + wcs * 64 + j] + red[256 + (2 + wcs) * 64 + j];
      P1[(size_t)(colBase + tid) * NRBLK + rblk] = s1;
      P2[(size_t)(colBase + tid) * NRBLK + rblk] = s2;
    }
  }

  if (MODE == 2) {
    const int b = rblk >> 6;   // 64 row-blocks per batch
#pragma unroll
    for (int n = 0; n < 4; ++n) {
      int col  = colBase + wc * 64 + n * 16 + lr;
      float sc = Sc[b * FOUT + col];
      float tc = Tc[b * FOUT + col];
#pragma unroll
      for (int m = 0; m < 4; ++m) {
        size_t row = rowBase + wr * 64 + m * 16 + lg * 4;
#pragma unroll
        for (int r = 0; r < 4; ++r)
          Y[(row + r) * (size_t)FOUT + col] = fmaf(acc[m][n][r], sc, tc);
      }
    }
  }
}

// One wave per (b,o); coalesced 64-lane read over rblk, shuffle reduce.
__global__ void reduce_stats(const float* __restrict__ P1, const float* __restrict__ P2,
                             const float* __restrict__ gamma, const float* __restrict__ beta,
                             float* __restrict__ Sc, float* __restrict__ Tc) {
  int p = blockIdx.x * 4 + (threadIdx.x >> 6);   // 0..4095 = (b,o)
  int lane = threadIdx.x & 63;
  int b = p >> 8, o = p & 255;
  size_t base = (size_t)o * NRBLK + b * 64;
  float s1 = P1[base + lane];
  float s2 = P2[base + lane];
#pragma unroll
  for (int off = 32; off; off >>= 1) {
    s1 += __shfl_xor(s1, off);
    s2 += __shfl_xor(s2, off);
  }
  if (lane == 0) {
    float mean = s1 * (1.f / (float)NDIM);
    float var  = s2 * (1.f / (float)NDIM) - mean * mean;
    float g    = gamma[o] * rsqrtf(var + 1e-5f);
    Sc[p] = g;
    Tc[p] = beta[o] - mean * g;
  }
}

// Elementwise normalize of materialized y (Plan A).
__global__ void normalize_y(const float4* __restrict__ Yv,
                            const float* __restrict__ Sc, const float* __restrict__ Tc,
                            float4* __restrict__ Ov) {
  const int total = (BDIM * NDIM * FOUT) / 4;  // 8,388,608
  for (int i = blockIdx.x * blockDim.x + threadIdx.x; i < total;
       i += gridDim.x * blockDim.x) {
    float4 y = Yv[i];
    size_t e = (size_t)i * 4;
    int o = (int)(e & 255);
    int b = (int)(e >> 21);
    const float4 s = *(const float4*)(Sc + b * 256 + o);
    const float4 t = *(const float4*)(Tc + b * 256 + o);
    float4 r;
    r.x = fmaf(y.x, s.x, t.x);
    r.y = fmaf(y.y, s.y, t.y);
    r.z = fmaf(y.z, s.z, t.z);
    r.w = fmaf(y.w, s.w, t.w);
    Ov[i] = r;
  }
}

extern "C" void kernel_launch(void* const* d_in, const int* in_sizes, int n_in,
                              void* d_out, int out_size, void* d_ws, size_t ws_size,
                              hipStream_t stream) {
  const float* X     = (const float*)d_in[0];
  const float* W     = (const float*)d_in[1];
  // d_in[2] = bias: cancelled exactly by BN mean subtraction.
  const float* gamma = (const float*)d_in[3];
  const float* beta  = (const float*)d_in[4];
  float* out = (float*)d_out;
  char* ws = (char*)d_ws;

  const size_t yB  = (size_t)BDIM * NDIM * FOUT * 4;   // 134,217,728
  const size_t pB  = (size_t)FOUT * NRBLK * 4;         // 1,048,576
  const size_t scB = 4096 * 4;                         // 16,384
  const size_t wB  = (size_t)FOUT * FIN * 2;           // 131,072
  const size_t xB  = (size_t)BDIM * NDIM * FIN * 2;    // 67,108,864

  const size_t needAp = 2 * pB + 2 * scB + 2 * wB + 2 * xB;  // ~136.6 MB
  const size_t needA  = needAp + yB;                         // ~270.8 MB

  dim3 grid(NRBLK, NCBLK), blk(NTH);
  if (ws_size >= needA) {
    // Plan A: materialize y in ws, one GEMM pass + streaming normalize.
    float* Y  = (float*)ws;
    float* P1 = (float*)(ws + yB);
    float* P2 = (float*)(ws + yB + pB);
    float* Sc = (float*)(ws + yB + 2 * pB);
    float* Tc = (float*)(ws + yB + 2 * pB + scB);
    unsigned short* Wh = (unsigned short*)(ws + yB + 2 * pB + 2 * scB);
    unsigned short* Wl = (unsigned short*)(ws + yB + 2 * pB + 2 * scB + wB);
    unsigned short* Xh = (unsigned short*)(ws + yB + 2 * pB + 2 * scB + 2 * wB);
    unsigned short* Xl = (unsigned short*)(ws + yB + 2 * pB + 2 * scB + 2 * wB + xB);
    split_w<<<32, 256, 0, stream>>>(W, Wh, Wl);
    split_x<<<2048, 256, 0, stream>>>(X, Xh, Xl);
    fused_gemm<0><<<grid, blk, 0, stream>>>(Xh, Xl, Wh, Wl, Y, P1, P2, nullptr, nullptr);
    reduce_stats<<<1024, 256, 0, stream>>>(P1, P2, gamma, beta, Sc, Tc);
    normalize_y<<<4096, 256, 0, stream>>>((const float4*)Y, Sc, Tc, (float4*)out);
  } else {
    // Plan A': stats pass + recompute pass (needs ~136.6 MB ws).
    float* P1 = (float*)ws;
    float* P2 = (float*)(ws + pB);
    float* Sc = (float*)(ws + 2 * pB);
    float* Tc = (float*)(ws + 2 * pB + scB);
    unsigned short* Wh = (unsigned short*)(ws + 2 * pB + 2 * scB);
    unsigned short* Wl = (unsigned short*)(ws + 2 * pB + 2 * scB + wB);
    unsigned short* Xh = (unsigned short*)(ws + 2 * pB + 2 * scB + 2 * wB);
    unsigned short* Xl = (unsigned short*)(ws + 2 * pB + 2 * scB + 2 * wB + xB);
    split_w<<<32, 256, 0, stream>>>(W, Wh, Wl);
    split_x<<<2048, 256, 0, stream>>>(X, Xh, Xl);
    fused_gemm<1><<<grid, blk, 0, stream>>>(Xh, Xl, Wh, Wl, nullptr, P1, P2, nullptr, nullptr);
    reduce_stats<<<1024, 256, 0, stream>>>(P1, P2, gamma, beta, Sc, Tc);
    fused_gemm<2><<<grid, blk, 0, stream>>>(Xh, Xl, Wh, Wl, out, P1, P2, Sc, Tc);
  }
}

// Round 8
// 325.767 us; speedup vs baseline: 1.1615x; 1.1381x over previous
//
#include <hip/hip_runtime.h>
#include <hip/hip_bf16.h>

// Fused Linear([16,8192,256] x [256,256]^T) + per-batch BatchNorm over N=8192.
// bf16x3 split-GEMM (hi*hi + hi*lo + lo*hi) => fp32-class accuracy on MFMA.
// Bias b dropped: BN mean-subtraction cancels any per-feature constant.
//
// R7 measured: conflicts 0->4.19M (swizzle bug: c^(r&3) degenerate on even
// rows at 64B stride), gemm 82us, total 371 (split_x pass ~55us overhead).
// R8: (1) swizzle fixed to c^((r>>1)&3) (2-way max per quarter-wave);
//     (2) kill split_x: BN=256/BM=64 =>每 X element split exactly once
//         in-kernel (reg-split A), W pre-split + gload_lds from image;
//     (3) NCBLK=1 => per-wave-complete stats, no LDS epilogue reduce.

typedef __attribute__((ext_vector_type(8))) __bf16 bf16x8;
typedef __attribute__((ext_vector_type(4))) float f32x4;
typedef __attribute__((ext_vector_type(8))) unsigned short us8;

#define BDIM   16
#define NDIM   8192
#define FIN    256
#define FOUT   256
#define BM     64
#define BN     256
#define BK     32
#define NTH    256
#define NRBLK  2048               // (BDIM*NDIM)/BM
#define NKS    8                  // FIN/BK
#define RPB    128                // row blocks per batch (NDIM/BM)
#define WTILEB 16384              // one ks-slab of W image: 256 rows x 64B

// Swizzled byte offset in a [rows]x32-bf16 tile (64B row): chunk c in 0..3.
// c' = c ^ ((r>>1)&3): over 16 consecutive rows each (parity, slot) pair is
// covered exactly 2x -> 2-way LDS access = free (m136).
__device__ __forceinline__ int swz64(int r, int c) {
  return r * 64 + ((c ^ ((r >> 1) & 3)) << 4);
}

__device__ __forceinline__ void split8(const float4 v0, const float4 v1,
                                       us8& h, us8& l) {
  float f[8] = {v0.x, v0.y, v0.z, v0.w, v1.x, v1.y, v1.z, v1.w};
#pragma unroll
  for (int i = 0; i < 8; ++i) {
    unsigned int u = __float_as_uint(f[i]);
    h[i] = (unsigned short)(u >> 16);
    float rem = f[i] - __uint_as_float(u & 0xFFFF0000u);
    l[i] = (unsigned short)(__float_as_uint(rem) >> 16);
  }
}

__device__ __forceinline__ void gload_lds16(const void* g, void* l) {
  __builtin_amdgcn_global_load_lds(
      (const __attribute__((address_space(1))) unsigned int*)g,
      (__attribute__((address_space(3))) unsigned int*)l, 16, 0, 0);
}

// W [256][256] fp32 (row = out col) -> Wh/Wl images [ks][256 rows][swz64].
__global__ void split_w(const float* __restrict__ W,
                        unsigned short* __restrict__ Wh,
                        unsigned short* __restrict__ Wl) {
  int i = blockIdx.x * blockDim.x + threadIdx.x;  // 0..8191 8-float chunks
  int row = i >> 5;
  int cg  = i & 31;
  int ks = cg >> 2, c = cg & 3;
  const float4* g = (const float4*)(W + (size_t)row * FIN + ks * BK + c * 8);
  float4 v0 = g[0], v1 = g[1];
  us8 h, l;
  split8(v0, v1, h, l);
  size_t off = (size_t)ks * WTILEB + swz64(row, c);
  *(us8*)((char*)Wh + off) = h;
  *(us8*)((char*)Wl + off) = l;
}

// MODE 0: write y + partial stats. MODE 1: stats only.
// MODE 2: apply per-(b,o) scale/shift, write normalized out.
template <int MODE>
__global__ __launch_bounds__(NTH, 4)
void fused_gemm(const float* __restrict__ X,
                const unsigned short* __restrict__ Wh,
                const unsigned short* __restrict__ Wl,
                float* __restrict__ Y,
                float* __restrict__ P1, float* __restrict__ P2,
                const float* __restrict__ Sc, const float* __restrict__ Tc) {
  __shared__ __align__(16) char lds[8192 + 2 * WTILEB];  // A 8K + B 32K
  char* Abh = lds;
  char* Abl = lds + 4096;
  char* Bbh = lds + 8192;
  char* Bbl = lds + 8192 + WTILEB;

  const int tid  = threadIdx.x;
  const int rblk = blockIdx.x;            // 0..2047
  const size_t rowBase = (size_t)rblk * BM;
  const int wid = tid >> 6, lane = tid & 63;
  const int lg = lane >> 4, lr = lane & 15;
  // wave wid owns cols wid*64 .. wid*64+63, all 64 rows.

  f32x4 acc[4][4];
#pragma unroll
  for (int m = 0; m < 4; ++m)
#pragma unroll
    for (int n = 0; n < 4; ++n) acc[m][n] = f32x4{0.f, 0.f, 0.f, 0.f};

  const int ar = tid >> 2, ac = tid & 3;  // this thread's A-stage row/chunk

  for (int ks = 0; ks < NKS; ++ks) {
    // ---- stage B (pre-split, pre-swizzled image): pure DMA ----
#pragma unroll
    for (int j = 0; j < 4; ++j) {
      int so = wid * 4096 + j * 1024;
      int go = ks * WTILEB + so + lane * 16;
      gload_lds16((const char*)Wh + go, Bbh + so);
      gload_lds16((const char*)Wl + go, Bbl + so);
    }
    // ---- stage A: read fp32, split in-regs, swizzled ds_write ----
    {
      const float4* g =
          (const float4*)(X + (rowBase + ar) * (size_t)FIN + ks * BK + ac * 8);
      float4 v0 = g[0], v1 = g[1];
      us8 h, l;
      split8(v0, v1, h, l);
      int boff = swz64(ar, ac);
      *(us8*)(Abh + boff) = h;
      *(us8*)(Abl + boff) = l;
    }
    __syncthreads();
    // ---- compute: K=32 slab, 4x4 frags, 3 products ----
    bf16x8 ah[4], al[4], bh[4], bl[4];
#pragma unroll
    for (int m = 0; m < 4; ++m) {
      int boff = swz64(m * 16 + lr, lg);
      ah[m] = *(const bf16x8*)(Abh + boff);
      al[m] = *(const bf16x8*)(Abl + boff);
    }
#pragma unroll
    for (int n = 0; n < 4; ++n) {
      int boff = swz64(wid * 64 + n * 16 + lr, lg);
      bh[n] = *(const bf16x8*)(Bbh + boff);
      bl[n] = *(const bf16x8*)(Bbl + boff);
    }
#pragma unroll
    for (int m = 0; m < 4; ++m)
#pragma unroll
      for (int n = 0; n < 4; ++n) {
        acc[m][n] = __builtin_amdgcn_mfma_f32_16x16x32_bf16(ah[m], bh[n], acc[m][n], 0, 0, 0);
        acc[m][n] = __builtin_amdgcn_mfma_f32_16x16x32_bf16(ah[m], bl[n], acc[m][n], 0, 0, 0);
        acc[m][n] = __builtin_amdgcn_mfma_f32_16x16x32_bf16(al[m], bh[n], acc[m][n], 0, 0, 0);
      }
    __syncthreads();
  }

  if (MODE == 0) {
#pragma unroll
    for (int m = 0; m < 4; ++m) {
      size_t row = rowBase + m * 16 + lg * 4;
#pragma unroll
      for (int n = 0; n < 4; ++n) {
        int col = wid * 64 + n * 16 + lr;
#pragma unroll
        for (int r = 0; r < 4; ++r)
          Y[(row + r) * (size_t)FOUT + col] = acc[m][n][r];
      }
    }
  }

  if (MODE <= 1) {
    // column partials over this block's 64 rows; wave-complete (NCBLK=1).
#pragma unroll
    for (int n = 0; n < 4; ++n) {
      float s1 = 0.f, s2 = 0.f;
#pragma unroll
      for (int m = 0; m < 4; ++m)
#pragma unroll
        for (int r = 0; r < 4; ++r) {
          float v = acc[m][n][r];
          s1 += v; s2 += v * v;
        }
      s1 += __shfl_xor(s1, 16);
      s1 += __shfl_xor(s1, 32);
      s2 += __shfl_xor(s2, 16);
      s2 += __shfl_xor(s2, 32);
      if (lg == 0) {
        int col = wid * 64 + n * 16 + lr;
        P1[(size_t)col * NRBLK + rblk] = s1;
        P2[(size_t)col * NRBLK + rblk] = s2;
      }
    }
  }

  if (MODE == 2) {
    const int b = rblk >> 7;   // RPB=128 row-blocks per batch
#pragma unroll
    for (int n = 0; n < 4; ++n) {
      int col  = wid * 64 + n * 16 + lr;
      float sc = Sc[b * FOUT + col];
      float tc = Tc[b * FOUT + col];
#pragma unroll
      for (int m = 0; m < 4; ++m) {
        size_t row = rowBase + m * 16 + lg * 4;
#pragma unroll
        for (int r = 0; r < 4; ++r)
          Y[(row + r) * (size_t)FOUT + col] = fmaf(acc[m][n][r], sc, tc);
      }
    }
  }
}

// One wave per (b,o); coalesced reads over 128 rblks, shuffle reduce.
__global__ void reduce_stats(const float* __restrict__ P1, const float* __restrict__ P2,
                             const float* __restrict__ gamma, const float* __restrict__ beta,
                             float* __restrict__ Sc, float* __restrict__ Tc) {
  int p = blockIdx.x * 4 + (threadIdx.x >> 6);   // 0..4095 = (b,o)
  int lane = threadIdx.x & 63;
  int b = p >> 8, o = p & 255;
  size_t base = (size_t)o * NRBLK + b * RPB;
  float s1 = P1[base + lane] + P1[base + 64 + lane];
  float s2 = P2[base + lane] + P2[base + 64 + lane];
#pragma unroll
  for (int off = 32; off; off >>= 1) {
    s1 += __shfl_xor(s1, off);
    s2 += __shfl_xor(s2, off);
  }
  if (lane == 0) {
    float mean = s1 * (1.f / (float)NDIM);
    float var  = s2 * (1.f / (float)NDIM) - mean * mean;
    float g    = gamma[o] * rsqrtf(var + 1e-5f);
    Sc[p] = g;
    Tc[p] = beta[o] - mean * g;
  }
}

// Elementwise normalize of materialized y (Plan A).
__global__ void normalize_y(const float4* __restrict__ Yv,
                            const float* __restrict__ Sc, const float* __restrict__ Tc,
                            float4* __restrict__ Ov) {
  const int total = (BDIM * NDIM * FOUT) / 4;  // 8,388,608
  for (int i = blockIdx.x * blockDim.x + threadIdx.x; i < total;
       i += gridDim.x * blockDim.x) {
    float4 y = Yv[i];
    size_t e = (size_t)i * 4;
    int o = (int)(e & 255);
    int b = (int)(e >> 21);
    const float4 s = *(const float4*)(Sc + b * 256 + o);
    const float4 t = *(const float4*)(Tc + b * 256 + o);
    float4 r;
    r.x = fmaf(y.x, s.x, t.x);
    r.y = fmaf(y.y, s.y, t.y);
    r.z = fmaf(y.z, s.z, t.z);
    r.w = fmaf(y.w, s.w, t.w);
    Ov[i] = r;
  }
}

extern "C" void kernel_launch(void* const* d_in, const int* in_sizes, int n_in,
                              void* d_out, int out_size, void* d_ws, size_t ws_size,
                              hipStream_t stream) {
  const float* X     = (const float*)d_in[0];
  const float* W     = (const float*)d_in[1];
  // d_in[2] = bias: cancelled exactly by BN mean subtraction.
  const float* gamma = (const float*)d_in[3];
  const float* beta  = (const float*)d_in[4];
  float* out = (float*)d_out;
  char* ws = (char*)d_ws;

  const size_t yB  = (size_t)BDIM * NDIM * FOUT * 4;   // 134,217,728
  const size_t pB  = (size_t)FOUT * NRBLK * 4;         // 2,097,152
  const size_t scB = 4096 * 4;                         // 16,384
  const size_t wB  = (size_t)FOUT * FIN * 2;           // 131,072

  const size_t needAp = 2 * pB + 2 * scB + 2 * wB;     // ~4.5 MB
  const size_t needA  = needAp + yB;                   // ~139 MB

  dim3 grid(NRBLK), blk(NTH);
  if (ws_size >= needA) {
    // Plan A: materialize y in ws, one GEMM pass + streaming normalize.
    float* Y  = (float*)ws;
    float* P1 = (float*)(ws + yB);
    float* P2 = (float*)(ws + yB + pB);
    float* Sc = (float*)(ws + yB + 2 * pB);
    float* Tc = (float*)(ws + yB + 2 * pB + scB);
    unsigned short* Wh = (unsigned short*)(ws + yB + 2 * pB + 2 * scB);
    unsigned short* Wl = (unsigned short*)(ws + yB + 2 * pB + 2 * scB + wB);
    split_w<<<32, 256, 0, stream>>>(W, Wh, Wl);
    fused_gemm<0><<<grid, blk, 0, stream>>>(X, Wh, Wl, Y, P1, P2, nullptr, nullptr);
    reduce_stats<<<1024, 256, 0, stream>>>(P1, P2, gamma, beta, Sc, Tc);
    normalize_y<<<4096, 256, 0, stream>>>((const float4*)Y, Sc, Tc, (float4*)out);
  } else {
    // Plan A': stats pass + recompute pass (needs ~4.5 MB ws).
    float* P1 = (float*)ws;
    float* P2 = (float*)(ws + pB);
    float* Sc = (float*)(ws + 2 * pB);
    float* Tc = (float*)(ws + 2 * pB + scB);
    unsigned short* Wh = (unsigned short*)(ws + 2 * pB + 2 * scB);
    unsigned short* Wl = (unsigned short*)(ws + 2 * pB + 2 * scB + wB);
    split_w<<<32, 256, 0, stream>>>(W, Wh, Wl);
    fused_gemm<1><<<grid, blk, 0, stream>>>(X, Wh, Wl, nullptr, P1, P2, nullptr, nullptr);
    reduce_stats<<<1024, 256, 0, stream>>>(P1, P2, gamma, beta, Sc, Tc);
    fused_gemm<2><<<grid, blk, 0, stream>>>(X, Wh, Wl, out, P1, P2, Sc, Tc);
  }
}